// Round 6
// baseline (430.128 us; speedup 1.0000x reference)
//
#include <hip/hip_runtime.h>
#include <math.h>

#define DEVI static __device__ __forceinline__

constexpr int Bn = 4, Cn = 4, Pn = 16384, Sn = 8192, Kn = 16;
constexpr float GN_N = 131072.0f;   // S*K per (b,channel)
constexpr int PART_STRIDE = 96;     // 79 used
constexpr int ST_CHUNKS = 64;       // k_stats grid.x

typedef float v2f __attribute__((ext_vector_type(2)));

// non-contracted f32 ops (exact pd must match np's mul/add order)
DEVI float mulrn(float a, float b){ return __fmul_rn(a, b); }
DEVI float addrn(float a, float b){ return __fadd_rn(a, b); }
DEVI float subrn(float a, float b){ return __fsub_rn(a, b); }
DEVI float leaky(float v, float s){ return v >= 0.0f ? v : s * v; }

// ---------------- K1: pack coords + norm into float4 ----------------
__global__ void k_pack(const float* __restrict__ x, float4* __restrict__ pk){
  int i = blockIdx.x * 256 + threadIdx.x;       // 0 .. B*P-1
  int b = i >> 14, p = i & (Pn - 1);
  const float* xb = x + (size_t)b * Cn * Pn;
  float x0 = xb[p], x1 = xb[Pn + p], x2 = xb[2 * Pn + p];
  float n = addrn(addrn(mulrn(x0, x0), mulrn(x1, x1)), mulrn(x2, x2));
  pk[i] = make_float4(x0, x1, x2, n);
}

// ---------------- K2: stable top-16 per (b,s) ----------------
// 16-lane groups, 4 queries/wave, 4 cands/lane/step (256 steps).
// SCREEN: contracted packed fma (compiler-selected v_pk_fma_f32, no asm),
// threshold slack 1e-2 absolute covers contraction error rigorously.
// EXACT pd (np rounding order) recomputed only in the rare insert path from
// shuffled candidate components. Top-16 sorted desc, 1 rank/lane.
__launch_bounds__(1024, 2)
__global__ void k_topk(const float4* __restrict__ pk, const int* __restrict__ perm,
                       int* __restrict__ idx){
  // entry e = st*32 + u*16 + l : pair (lo = st*64 + u*32 + l, hi = lo+16)
  // tileA[e]=(x_lo,x_hi,y_lo,y_hi)  tileB[e]=(z_lo,z_hi,-w_lo,-w_hi)
  __shared__ float4 tileA[2048];
  __shared__ float4 tileB[2048];
  const int b = blockIdx.y;
  const int tid = threadIdx.x;
  const int lane16 = tid & 15;
  const bool lane0 = (lane16 == 0);
  const int g = (tid & 63) >> 4;                // group within wave
  const unsigned long long gmask = 0xFFFFull << (g * 16);
  const int s = blockIdx.x * 64 + (tid >> 4);

  const int q = perm[b * Sn + s];
  const float4 sv = pk[b * Pn + q];
  const float sn = sv.w;
  const float svx = sv.x, svy = sv.y, svz = sv.z;
  const v2f sx2 = {2.0f * svx, 2.0f * svx};
  const v2f sy2 = {2.0f * svy, 2.0f * svy};
  const v2f sz2 = {2.0f * svz, 2.0f * svz};

  float lv = -INFINITY;  int li = 0;            // my rank's (value, index)
  float T = -INFINITY;                          // screen threshold (L-space)

  // exact np-order pd in insert path; contracted screen covered by slack
#define PROC(LH, CX, CY, CZ, CNW, OFF)                                       \
  { unsigned long long mm = __ballot((LH) > T) & gmask;                      \
    while (mm){                                                              \
      const int src = __builtin_ctzll(mm);                                   \
      mm &= mm - 1;                                                          \
      const float cx = __shfl((CX), src);                                    \
      const float cy = __shfl((CY), src);                                    \
      const float cz = __shfl((CZ), src);                                    \
      const float cnw = __shfl((CNW), src);                                  \
      const float dot = addrn(addrn(mulrn(cx, svx), mulrn(cy, svy)),         \
                              mulrn(cz, svz));                               \
      const float cv = subrn(fmaf(2.0f, dot, cnw), sn);   /* exact pd */     \
      const int   ci = cbase + (OFF) + (src & 15);                           \
      const float upv = __shfl_up(lv, 1, 16);                                \
      const int   upi = __shfl_up(li, 1, 16);                                \
      const bool keep = (lv >= cv);                                          \
      const bool ins  = (!keep) && (lane0 || upv >= cv);                     \
      lv = keep ? lv : (ins ? cv : upv);                                     \
      li = keep ? li : (ins ? ci : upi);                                     \
    } }

  for (int t = 0; t < 4; ++t){
    __syncthreads();
    const int pb = b * Pn + t * 4096;
    for (int e = tid; e < 2048; e += 1024){
      const int st0 = e >> 5, u0 = (e >> 4) & 1, l0i = e & 15;
      const int c0 = st0 * 64 + u0 * 32 + l0i;
      const float4 lo = pk[pb + c0];
      const float4 hi = pk[pb + c0 + 16];
      tileA[e] = make_float4(lo.x, hi.x, lo.y, hi.y);
      tileB[e] = make_float4(lo.z, hi.z, -lo.w, -hi.w);
    }
    __syncthreads();

#pragma unroll 2
    for (int st = 0; st < 64; ++st){
      const int e0 = st * 32 + lane16;
      const float4 A0 = tileA[e0],      B0 = tileB[e0];
      const float4 A1 = tileA[e0 + 16], B1 = tileB[e0 + 16];
      // contracted packed screen: L = fma(x,2sx, fma(y,2sy, fma(z,2sz, -w)))
      const v2f xp0 = {A0.x, A0.y}, yp0 = {A0.z, A0.w};
      const v2f zp0 = {B0.x, B0.y}, nw0 = {B0.z, B0.w};
      const v2f xp1 = {A1.x, A1.y}, yp1 = {A1.z, A1.w};
      const v2f zp1 = {B1.x, B1.y}, nw1 = {B1.z, B1.w};
      const v2f L0 = __builtin_elementwise_fma(xp0, sx2,
                       __builtin_elementwise_fma(yp0, sy2,
                         __builtin_elementwise_fma(zp0, sz2, nw0)));
      const v2f L1 = __builtin_elementwise_fma(xp1, sx2,
                       __builtin_elementwise_fma(yp1, sy2,
                         __builtin_elementwise_fma(zp1, sz2, nw1)));
      const float pm = fmaxf(fmaxf(fmaxf(L0.x, L0.y), L1.x), L1.y);

      if (__ballot(pm > T)){
        const int cbase = t * 4096 + st * 64;
        PROC(L0.x, A0.x, A0.z, B0.x, B0.z, 0)
        PROC(L0.y, A0.y, A0.w, B0.y, B0.w, 16)
        PROC(L1.x, A1.x, A1.z, B1.x, B1.z, 32)
        PROC(L1.y, A1.y, A1.w, B1.y, B1.w, 48)
        const float tau = __shfl(lv, 15, 16);
        // 1e-2 abs slack >= contraction error for |coord| up to ~70;
        // admits only ~7 extra near-threshold candidates per query.
        T = subrn(addrn(tau, sn), fmaf(fabsf(tau) + fabsf(sn), 1e-6f, 1e-2f));
      }
    }
  }
#undef PROC
  idx[(b * Sn + s) * Kn + lane16] = li;
}

// scramble: x1[b,c,s',k'] = x[b,c, idx[b, (16s'+k') & 8191, (16s'+k') >> 13]]
DEVI int idxq(const int* __restrict__ idxb, int f){
  return idxb[(f & (Sn - 1)) * Kn + (f >> 13)];
}

DEVI float wred(float v){
  v += __shfl_down(v, 32); v += __shfl_down(v, 16); v += __shfl_down(v, 8);
  v += __shfl_down(v, 4);  v += __shfl_down(v, 2);  v += __shfl_down(v, 1);
  return v;
}

// ---------------- K3: GN moment accumulation ----------------
// grid (64, B), block 256: thread -> (sp, kq); sp = chunk*128 + tid>>1, 8 k's each.
__global__ void k_stats(const float4* __restrict__ pk, const float* __restrict__ x,
                        const int* __restrict__ idx, float* __restrict__ part){
  const int b = blockIdx.y, chunk = blockIdx.x, tid = threadIdx.x;
  const int sp = chunk * 128 + (tid >> 1);
  const int kq = tid & 1;
  const int* idxb = idx + b * Sn * Kn;
  const float* xw = x + ((size_t)b * Cn + 3) * Pn;

  float M10[55], mu10[10], M4[10], mu4[4];
#pragma unroll
  for (int i = 0; i < 55; ++i) M10[i] = 0.f;
#pragma unroll
  for (int i = 0; i < 10; ++i){ mu10[i] = 0.f; M4[i] = 0.f; }
#pragma unroll
  for (int i = 0; i < 4; ++i) mu4[i] = 0.f;

  const int qc = idxq(idxb, sp * 16);
  const float4 cv = pk[b * Pn + qc];

  for (int k = kq * 8; k < kq * 8 + 8; ++k){
    const int qn = idxq(idxb, sp * 16 + k);
    const float4 pv = pk[b * Pn + qn];
    const float pw = xw[qn];
    const float dx = subrn(pv.x, cv.x), dy = subrn(pv.y, cv.y), dz = subrn(pv.z, cv.z);
    const float temp = sqrtf(addrn(addrn(mulrn(dx, dx), mulrn(dy, dy)), mulrn(dz, dz)));
    const float E[10] = {pv.x, pv.y, pv.z, cv.x, cv.y, cv.z, dx, dy, dz, temp};
    const float X[4]  = {pv.x, pv.y, pv.z, pw};
    int c = 0;
#pragma unroll
    for (int i = 0; i < 10; ++i){
      mu10[i] += E[i];
#pragma unroll
      for (int j = i; j < 10; ++j){ M10[c] += E[i] * E[j]; ++c; }
    }
    c = 0;
#pragma unroll
    for (int i = 0; i < 4; ++i){
      mu4[i] += X[i];
#pragma unroll
      for (int j = i; j < 4; ++j){ M4[c] += X[i] * X[j]; ++c; }
    }
  }

  __shared__ float red[4][80];
  const int wid = tid >> 6, ln = tid & 63;
#pragma unroll
  for (int i = 0; i < 55; ++i){ float v = wred(M10[i]); if (ln == 0) red[wid][i] = v; }
#pragma unroll
  for (int i = 0; i < 10; ++i){ float v = wred(mu10[i]); if (ln == 0) red[wid][55 + i] = v; }
#pragma unroll
  for (int i = 0; i < 10; ++i){ float v = wred(M4[i]); if (ln == 0) red[wid][65 + i] = v; }
#pragma unroll
  for (int i = 0; i < 4; ++i){ float v = wred(mu4[i]); if (ln == 0) red[wid][75 + i] = v; }
  __syncthreads();
  if (tid < 79){
    float sum = ((red[0][tid] + red[1][tid]) + red[2][tid]) + red[3][tid];
    part[(b * ST_CHUNKS + chunk) * PART_STRIDE + tid] = sum;
  }
}

// ---------------- K4: fold moments into per-(b,ch) scale/shift ----------------
// one block, 512 threads: phase1 parallel chunk-reduce (320 threads), phase2 fold.
__global__ void k_stats2(const float* __restrict__ part,
                         const float* __restrict__ pos_w, const float* __restrict__ conv_w,
                         const float* __restrict__ bn2_g, const float* __restrict__ bn2_b,
                         const float* __restrict__ bn_g,  const float* __restrict__ bn_b,
                         float2* __restrict__ stats){
  __shared__ float sacc[4][80];
  const int t = threadIdx.x;
  if (t < 320){
    const int bb = t / 80, i = t % 80;
    if (i < 79){
      float a = 0.f;
      for (int c = 0; c < ST_CHUNKS; ++c)
        a += part[(bb * ST_CHUNKS + c) * PART_STRIDE + i];
      sacc[bb][i] = a;
    }
  }
  __syncthreads();
  if (t >= 256) return;
  const int b = t >> 6, o = t & 63;
  const float* acc = sacc[b];
  float mean, ex2, gamma, beta;
  if (o < 32){                        // xc channels: conv path, bn_g/bn_b
    const float* w = conv_w + o * 4;
    float m = 0.f, e2 = 0.f; int id = 0;
#pragma unroll
    for (int i = 0; i < 4; ++i){
      m += w[i] * acc[75 + i];
#pragma unroll
      for (int j = i; j < 4; ++j){
        float t2 = w[i] * w[j] * acc[65 + id];
        e2 += (i == j) ? t2 : 2.0f * t2; ++id;
      }
    }
    mean = m / GN_N; ex2 = e2 / GN_N; gamma = bn_g[o]; beta = bn_b[o];
  } else {                            // pe channels: pos path, bn2_g/bn2_b
    const float* w = pos_w + (o - 32) * 10;
    float m = 0.f, e2 = 0.f; int id = 0;
#pragma unroll
    for (int i = 0; i < 10; ++i){
      m += w[i] * acc[55 + i];
#pragma unroll
      for (int j = i; j < 10; ++j){
        float t2 = w[i] * w[j] * acc[id];
        e2 += (i == j) ? t2 : 2.0f * t2; ++id;
      }
    }
    mean = m / GN_N; ex2 = e2 / GN_N; gamma = bn2_g[o - 32]; beta = bn2_b[o - 32];
  }
  const float var = fmaxf(ex2 - mean * mean, 0.f);
  const float rstd = 1.0f / sqrtf(var + 1e-5f);
  const float scale = rstd * gamma;
  stats[b * 64 + o] = make_float2(scale, beta - mean * scale);
}

// ---------------- K5: fused features + attention + output ----------------
// 16 lanes per s' (one (s',k') per lane); block 256 -> 16 s'.
__global__ void k_final(const float4* __restrict__ pk, const float* __restrict__ x,
                        const int* __restrict__ idx, const float2* __restrict__ stats,
                        const float* __restrict__ conv_w, const float* __restrict__ pos_w,
                        const float* __restrict__ att_w1, const float* __restrict__ att_w2,
                        const float* __restrict__ b1_w, const float* __restrict__ b2_w,
                        float* __restrict__ out){
  const int b = blockIdx.y;
  const int tid = threadIdx.x;
  const int k = tid & 15;
  const int sp = blockIdx.x * 16 + (tid >> 4);
  const int* idxb = idx + b * Sn * Kn;
  const float* xw = x + ((size_t)b * Cn + 3) * Pn;

  const int qn = idxq(idxb, sp * 16 + k);
  const float4 pv = pk[b * Pn + qn];
  const float pw = xw[qn];
  const float cx = __shfl(pv.x, 0, 16), cy = __shfl(pv.y, 0, 16);
  const float cz = __shfl(pv.z, 0, 16), cw = __shfl(pw, 0, 16);
  const float dx = subrn(pv.x, cx), dy = subrn(pv.y, cy), dz = subrn(pv.z, cz);
  const float temp = sqrtf(addrn(addrn(mulrn(dx, dx), mulrn(dy, dy)), mulrn(dz, dz)));
  const float E[10]  = {pv.x, pv.y, pv.z, cx, cy, cz, dx, dy, dz, temp};
  const float X4[4]  = {pv.x, pv.y, pv.z, pw};
  const float2* stb = stats + b * 64;

  float feat[64];
  for (int o = 0; o < 32; ++o){       // xc
    float v = 0.f;
#pragma unroll
    for (int c = 0; c < 4; ++c) v = fmaf(conv_w[o * 4 + c], X4[c], v);
    const float2 sc = stb[o];
    feat[o] = leaky(fmaf(v, sc.x, sc.y), 0.2f);
  }
  for (int o = 0; o < 32; ++o){       // pe
    float v = 0.f;
#pragma unroll
    for (int c = 0; c < 10; ++c) v = fmaf(pos_w[o * 10 + c], E[c], v);
    const float2 sc = stb[32 + o];
    feat[32 + o] = leaky(fmaf(v, sc.x, sc.y), 0.2f);
  }

  float logit = 0.f;
  for (int h = 0; h < 32; ++h){
    float v = 0.f;
#pragma unroll
    for (int c = 0; c < 64; ++c) v = fmaf(att_w1[h * 64 + c], feat[c], v);
    logit = fmaf(att_w2[h], leaky(v, 0.2f), logit);
  }
  float mx = logit;
  mx = fmaxf(mx, __shfl_xor(mx, 1, 16)); mx = fmaxf(mx, __shfl_xor(mx, 2, 16));
  mx = fmaxf(mx, __shfl_xor(mx, 4, 16)); mx = fmaxf(mx, __shfl_xor(mx, 8, 16));
  const float e = expf(logit - mx);
  float den = e;
  den += __shfl_xor(den, 1, 16); den += __shfl_xor(den, 2, 16);
  den += __shfl_xor(den, 4, 16); den += __shfl_xor(den, 8, 16);
  const float att = e / den;

#pragma unroll
  for (int c = 0; c < 64; ++c){       // pooled (replicated on all 16 lanes)
    float p = feat[c] * att;
    p += __shfl_xor(p, 1, 16); p += __shfl_xor(p, 2, 16);
    p += __shfl_xor(p, 4, 16); p += __shfl_xor(p, 8, 16);
    feat[c] = p;
  }

  const float X0[4] = {cx, cy, cz, cw};
  float* outb = out + (size_t)b * 68 * Sn;
#pragma unroll
  for (int jj = 0; jj < 4; ++jj){
    const int j = k * 4 + jj;
    float f1 = 0.f;
#pragma unroll
    for (int c = 0; c < 64; ++c) f1 = fmaf(b1_w[j * 64 + c], feat[c], f1);
    float f2 = 0.f;
#pragma unroll
    for (int c = 0; c < 4; ++c) f2 = fmaf(b2_w[j * 4 + c], X0[c], f2);
    outb[(size_t)(4 + j) * Sn + sp] = leaky(f1 + f2, 0.1f);
  }
  if (k == 0){
    outb[0 * Sn + sp] = cx; outb[1 * Sn + sp] = cy;
    outb[2 * Sn + sp] = cz; outb[3 * Sn + sp] = cw;
  }
}

extern "C" void kernel_launch(void* const* d_in, const int* in_sizes, int n_in,
                              void* d_out, int out_size, void* d_ws, size_t ws_size,
                              hipStream_t stream){
  const float* x      = (const float*)d_in[0];
  const int*   perm   = (const int*)d_in[1];
  const float* pos_w  = (const float*)d_in[3];
  const float* bn2_g  = (const float*)d_in[4];
  const float* bn2_b  = (const float*)d_in[5];
  const float* conv_w = (const float*)d_in[6];
  const float* bn_g   = (const float*)d_in[7];
  const float* bn_b   = (const float*)d_in[8];
  const float* att_w1 = (const float*)d_in[9];
  const float* att_w2 = (const float*)d_in[10];
  const float* b1_w   = (const float*)d_in[11];
  const float* b2_w   = (const float*)d_in[12];
  float* out = (float*)d_out;

  char* ws = (char*)d_ws;
  int*    idx   = (int*)ws;                       // 2 MiB
  float4* pk    = (float4*)(ws + 2097152);        // 1 MiB
  float*  part  = (float*)(ws + 3145728);         // 96 KiB
  float2* stats = (float2*)(ws + 3342336);        // 2 KiB

  hipLaunchKernelGGL(k_pack,   dim3(256),            dim3(256),  0, stream, x, pk);
  hipLaunchKernelGGL(k_topk,   dim3(128, 4),         dim3(1024), 0, stream, pk, perm, idx);
  hipLaunchKernelGGL(k_stats,  dim3(ST_CHUNKS, 4),   dim3(256),  0, stream, pk, x, idx, part);
  hipLaunchKernelGGL(k_stats2, dim3(1),              dim3(512),  0, stream, part, pos_w, conv_w,
                     bn2_g, bn2_b, bn_g, bn_b, stats);
  hipLaunchKernelGGL(k_final,  dim3(512, 4),         dim3(256),  0, stream, pk, x, idx, stats,
                     conv_w, pos_w, att_w1, att_w2, b1_w, b2_w, out);
}

// Round 7
// 348.844 us; speedup vs baseline: 1.2330x; 1.2330x over previous
//
#include <hip/hip_runtime.h>
#include <math.h>

#define DEVI static __device__ __forceinline__

constexpr int Bn = 4, Cn = 4, Pn = 16384, Sn = 8192, Kn = 16;
constexpr float GN_N = 131072.0f;   // S*K per (b,channel)
constexpr int PART_STRIDE = 96;     // 79 used
constexpr int ST_CHUNKS = 128;      // k_stats grid.x

typedef float v2f __attribute__((ext_vector_type(2)));

// non-contracted f32 ops (exact pd must match np's mul/add order)
DEVI float mulrn(float a, float b){ return __fmul_rn(a, b); }
DEVI float addrn(float a, float b){ return __fadd_rn(a, b); }
DEVI float subrn(float a, float b){ return __fsub_rn(a, b); }
DEVI float leaky(float v, float s){ return v >= 0.0f ? v : s * v; }

DEVI v2f pkmul(v2f a, v2f b){ v2f d; asm("v_pk_mul_f32 %0, %1, %2" : "=v"(d) : "v"(a), "v"(b)); return d; }
DEVI v2f pkadd(v2f a, v2f b){ v2f d; asm("v_pk_add_f32 %0, %1, %2" : "=v"(d) : "v"(a), "v"(b)); return d; }
DEVI v2f pkfma(v2f a, v2f b, v2f c){ v2f d; asm("v_pk_fma_f32 %0, %1, %2, %3" : "=v"(d) : "v"(a), "v"(b), "v"(c)); return d; }

// DPP row_shr:1 == shfl_up(x,1,16): 16-lane groups coincide with DPP rows;
// lane0-of-row gets its own value (old), which the insert logic overrides.
DEVI float dpp_up1f(float x){
  int xi = __builtin_bit_cast(int, x);
  int r = __builtin_amdgcn_update_dpp(xi, xi, 0x111, 0xF, 0xF, false);
  return __builtin_bit_cast(float, r);
}
DEVI int dpp_up1i(int x){
  return __builtin_amdgcn_update_dpp(x, x, 0x111, 0xF, 0xF, false);
}
// lane (i|15) broadcast within each 16-lane group: BitMode or_mask=15,and=0x1F
DEVI float swz15(float x){
  int xi = __builtin_bit_cast(int, x);
  int r = __builtin_amdgcn_ds_swizzle(xi, 0x1FF);
  return __builtin_bit_cast(float, r);
}

// ---------------- K1: pack coords + norm into float4 ----------------
__global__ void k_pack(const float* __restrict__ x, float4* __restrict__ pk){
  int i = blockIdx.x * 256 + threadIdx.x;       // 0 .. B*P-1
  int b = i >> 14, p = i & (Pn - 1);
  const float* xb = x + (size_t)b * Cn * Pn;
  float x0 = xb[p], x1 = xb[Pn + p], x2 = xb[2 * Pn + p];
  float n = addrn(addrn(mulrn(x0, x0), mulrn(x1, x1)), mulrn(x2, x2));
  pk[i] = make_float4(x0, x1, x2, n);
}

// ---------------- K2: stable top-16 per (b,s) ----------------
// R5 structure (16-lane groups, 4 queries/wave, exact-rn pk screen, 4
// cands/lane/step) with the insert path moved off the LDS pipe:
// shfl_up -> DPP row_shr:1, tau -> ds_swizzle. Sorted desc, 1 rank/lane.
__launch_bounds__(1024, 2)
__global__ void k_topk(const float4* __restrict__ pk, const int* __restrict__ perm,
                       int* __restrict__ idx){
  // entry e = st*32 + u*16 + l : pair (lo = st*64 + u*32 + l, hi = lo+16)
  // tileA[e]=(x_lo,x_hi,y_lo,y_hi)  tileB[e]=(z_lo,z_hi,-w_lo,-w_hi)
  __shared__ float4 tileA[2048];
  __shared__ float4 tileB[2048];
  const int b = blockIdx.y;
  const int tid = threadIdx.x;
  const int lane16 = tid & 15;
  const bool lane0 = (lane16 == 0);
  const int g = (tid & 63) >> 4;                // group within wave
  const unsigned long long gmask = 0xFFFFull << (g * 16);
  const int s = blockIdx.x * 64 + (tid >> 4);

  const int q = perm[b * Sn + s];
  const float4 sv = pk[b * Pn + q];
  const float sn = sv.w;
  const v2f sxx = {sv.x, sv.x}, syy = {sv.y, sv.y}, szz = {sv.z, sv.z};
  const v2f two2 = {2.0f, 2.0f};

  float lv = -INFINITY;  int li = 0;            // my rank's (value, index)
  float T = -INFINITY;                          // screen threshold (L-space)

#define PROC(LH, U, H)                                                       \
  { unsigned long long mm = __ballot((LH) > T) & gmask;                      \
    while (mm){                                                              \
      const int src = __builtin_ctzll(mm);                                   \
      mm &= mm - 1;                                                          \
      const float cL = __shfl((LH), src);                                    \
      const float cv = subrn(cL, sn);          /* exact pd */                \
      const int   ci = cbase + (U) * 32 + (H) * 16 + (src & 15);             \
      const float upv = dpp_up1f(lv);                                        \
      const int   upi = dpp_up1i(li);                                        \
      const bool keep = (lv >= cv);                                          \
      const bool ins  = (!keep) && (lane0 || upv >= cv);                     \
      lv = keep ? lv : (ins ? cv : upv);                                     \
      li = keep ? li : (ins ? ci : upi);                                     \
    } }

  for (int t = 0; t < 4; ++t){
    __syncthreads();
    const int pb = b * Pn + t * 4096;
    for (int e = tid; e < 2048; e += 1024){
      const int st0 = e >> 5, u0 = (e >> 4) & 1, l0i = e & 15;
      const int c0 = st0 * 64 + u0 * 32 + l0i;
      const float4 lo = pk[pb + c0];
      const float4 hi = pk[pb + c0 + 16];
      tileA[e] = make_float4(lo.x, hi.x, lo.y, hi.y);
      tileB[e] = make_float4(lo.z, hi.z, -lo.w, -hi.w);
    }
    __syncthreads();

#pragma unroll 2
    for (int st = 0; st < 64; ++st){
      const int e0 = st * 32 + lane16;
      const float4 A0 = tileA[e0],      B0 = tileB[e0];
      const float4 A1 = tileA[e0 + 16], B1 = tileB[e0 + 16];
      // exact-rn pd stream (order matches np): ((x*sx + y*sy) + z*sz), L=2*dot-w
      v2f m0 = pkmul((v2f){A0.x, A0.y}, sxx);
      v2f n0 = pkmul((v2f){A0.z, A0.w}, syy);
      v2f s0 = pkadd(m0, n0);
      v2f z0 = pkmul((v2f){B0.x, B0.y}, szz);
      v2f d0 = pkadd(s0, z0);
      const v2f L0 = pkfma(two2, d0, (v2f){B0.z, B0.w});
      v2f m1 = pkmul((v2f){A1.x, A1.y}, sxx);
      v2f n1 = pkmul((v2f){A1.z, A1.w}, syy);
      v2f s1 = pkadd(m1, n1);
      v2f z1 = pkmul((v2f){B1.x, B1.y}, szz);
      v2f d1 = pkadd(s1, z1);
      const v2f L1 = pkfma(two2, d1, (v2f){B1.z, B1.w});
      const float pm = fmaxf(fmaxf(fmaxf(L0.x, L0.y), L1.x), L1.y);

      if (__ballot(pm > T)){
        const int cbase = t * 4096 + st * 64;
        PROC(L0.x, 0, 0)
        PROC(L0.y, 0, 1)
        PROC(L1.x, 1, 0)
        PROC(L1.y, 1, 1)
        const float tau = swz15(lv);
        // slack >= 8x the 2-ulp screen discrepancy at all magnitudes
        T = subrn(addrn(tau, sn), fmaf(fabsf(tau) + fabsf(sn), 1e-6f, 1e-30f));
      }
    }
  }
#undef PROC
  idx[(b * Sn + s) * Kn + lane16] = li;
}

// scramble: x1[b,c,s',k'] = x[b,c, idx[b, (16s'+k') & 8191, (16s'+k') >> 13]]
DEVI int idxq(const int* __restrict__ idxb, int f){
  return idxb[(f & (Sn - 1)) * Kn + (f >> 13)];
}

DEVI float wred(float v){
  v += __shfl_down(v, 32); v += __shfl_down(v, 16); v += __shfl_down(v, 8);
  v += __shfl_down(v, 4);  v += __shfl_down(v, 2);  v += __shfl_down(v, 1);
  return v;
}

// ---------------- K3: GN moment accumulation ----------------
// grid (128, B), block 256: thread -> (sp, kq); sp = chunk*64 + tid>>2, 4 k's.
__global__ void k_stats(const float4* __restrict__ pk, const float* __restrict__ x,
                        const int* __restrict__ idx, float* __restrict__ part){
  const int b = blockIdx.y, chunk = blockIdx.x, tid = threadIdx.x;
  const int sp = chunk * 64 + (tid >> 2);
  const int kq = tid & 3;
  const int* idxb = idx + b * Sn * Kn;
  const float* xw = x + ((size_t)b * Cn + 3) * Pn;

  float M10[55], mu10[10], M4[10], mu4[4];
#pragma unroll
  for (int i = 0; i < 55; ++i) M10[i] = 0.f;
#pragma unroll
  for (int i = 0; i < 10; ++i){ mu10[i] = 0.f; M4[i] = 0.f; }
#pragma unroll
  for (int i = 0; i < 4; ++i) mu4[i] = 0.f;

  const int qc = idxq(idxb, sp * 16);
  const float4 cv = pk[b * Pn + qc];

#pragma unroll
  for (int kk = 0; kk < 4; ++kk){
    const int k = kq * 4 + kk;
    const int qn = idxq(idxb, sp * 16 + k);
    const float4 pv = pk[b * Pn + qn];
    const float pw = xw[qn];
    const float dx = subrn(pv.x, cv.x), dy = subrn(pv.y, cv.y), dz = subrn(pv.z, cv.z);
    const float temp = sqrtf(addrn(addrn(mulrn(dx, dx), mulrn(dy, dy)), mulrn(dz, dz)));
    const float E[10] = {pv.x, pv.y, pv.z, cv.x, cv.y, cv.z, dx, dy, dz, temp};
    const float X[4]  = {pv.x, pv.y, pv.z, pw};
    int c = 0;
#pragma unroll
    for (int i = 0; i < 10; ++i){
      mu10[i] += E[i];
#pragma unroll
      for (int j = i; j < 10; ++j){ M10[c] += E[i] * E[j]; ++c; }
    }
    c = 0;
#pragma unroll
    for (int i = 0; i < 4; ++i){
      mu4[i] += X[i];
#pragma unroll
      for (int j = i; j < 4; ++j){ M4[c] += X[i] * X[j]; ++c; }
    }
  }

  __shared__ float red[4][80];
  const int wid = tid >> 6, ln = tid & 63;
#pragma unroll
  for (int i = 0; i < 55; ++i){ float v = wred(M10[i]); if (ln == 0) red[wid][i] = v; }
#pragma unroll
  for (int i = 0; i < 10; ++i){ float v = wred(mu10[i]); if (ln == 0) red[wid][55 + i] = v; }
#pragma unroll
  for (int i = 0; i < 10; ++i){ float v = wred(M4[i]); if (ln == 0) red[wid][65 + i] = v; }
#pragma unroll
  for (int i = 0; i < 4; ++i){ float v = wred(mu4[i]); if (ln == 0) red[wid][75 + i] = v; }
  __syncthreads();
  if (tid < 79){
    float sum = ((red[0][tid] + red[1][tid]) + red[2][tid]) + red[3][tid];
    part[(b * ST_CHUNKS + chunk) * PART_STRIDE + tid] = sum;
  }
}

// ---------------- K4: fold moments into per-(b,ch) scale/shift ----------------
// one block, 640 threads: phase1 = 8 parallel (b,half) chunk-reductions,
// phase2 = combine halves, phase3 = fold (256 threads).
__global__ void k_stats2(const float* __restrict__ part,
                         const float* __restrict__ pos_w, const float* __restrict__ conv_w,
                         const float* __restrict__ bn2_g, const float* __restrict__ bn2_b,
                         const float* __restrict__ bn_g,  const float* __restrict__ bn_b,
                         float2* __restrict__ stats){
  __shared__ float phalf[8][80];
  __shared__ float sacc[4][80];
  const int t = threadIdx.x;
  if (t < 640){
    const int pair = t / 80, i = t % 80;      // pair = b*2 + half
    if (i < 79){
      const int bb = pair >> 1, half = pair & 1;
      float a = 0.f;
      for (int c = half * 64; c < half * 64 + 64; ++c)
        a += part[(bb * ST_CHUNKS + c) * PART_STRIDE + i];
      phalf[pair][i] = a;
    }
  }
  __syncthreads();
  if (t < 320){
    const int bb = t / 80, i = t % 80;
    if (i < 79) sacc[bb][i] = phalf[bb * 2][i] + phalf[bb * 2 + 1][i];
  }
  __syncthreads();
  if (t >= 256) return;
  const int b = t >> 6, o = t & 63;
  const float* acc = sacc[b];
  float mean, ex2, gamma, beta;
  if (o < 32){                        // xc channels: conv path, bn_g/bn_b
    const float* w = conv_w + o * 4;
    float m = 0.f, e2 = 0.f; int id = 0;
#pragma unroll
    for (int i = 0; i < 4; ++i){
      m += w[i] * acc[75 + i];
#pragma unroll
      for (int j = i; j < 4; ++j){
        float t2 = w[i] * w[j] * acc[65 + id];
        e2 += (i == j) ? t2 : 2.0f * t2; ++id;
      }
    }
    mean = m / GN_N; ex2 = e2 / GN_N; gamma = bn_g[o]; beta = bn_b[o];
  } else {                            // pe channels: pos path, bn2_g/bn2_b
    const float* w = pos_w + (o - 32) * 10;
    float m = 0.f, e2 = 0.f; int id = 0;
#pragma unroll
    for (int i = 0; i < 10; ++i){
      m += w[i] * acc[55 + i];
#pragma unroll
      for (int j = i; j < 10; ++j){
        float t2 = w[i] * w[j] * acc[id];
        e2 += (i == j) ? t2 : 2.0f * t2; ++id;
      }
    }
    mean = m / GN_N; ex2 = e2 / GN_N; gamma = bn2_g[o - 32]; beta = bn2_b[o - 32];
  }
  const float var = fmaxf(ex2 - mean * mean, 0.f);
  const float rstd = 1.0f / sqrtf(var + 1e-5f);
  const float scale = rstd * gamma;
  stats[b * 64 + o] = make_float2(scale, beta - mean * scale);
}

// ---------------- K5: fused features + attention + output ----------------
// 16 lanes per s' (one (s',k') per lane); block 256 -> 16 s'.
__global__ void k_final(const float4* __restrict__ pk, const float* __restrict__ x,
                        const int* __restrict__ idx, const float2* __restrict__ stats,
                        const float* __restrict__ conv_w, const float* __restrict__ pos_w,
                        const float* __restrict__ att_w1, const float* __restrict__ att_w2,
                        const float* __restrict__ b1_w, const float* __restrict__ b2_w,
                        float* __restrict__ out){
  const int b = blockIdx.y;
  const int tid = threadIdx.x;
  const int k = tid & 15;
  const int sp = blockIdx.x * 16 + (tid >> 4);
  const int* idxb = idx + b * Sn * Kn;
  const float* xw = x + ((size_t)b * Cn + 3) * Pn;

  const int qn = idxq(idxb, sp * 16 + k);
  const float4 pv = pk[b * Pn + qn];
  const float pw = xw[qn];
  const float cx = __shfl(pv.x, 0, 16), cy = __shfl(pv.y, 0, 16);
  const float cz = __shfl(pv.z, 0, 16), cw = __shfl(pw, 0, 16);
  const float dx = subrn(pv.x, cx), dy = subrn(pv.y, cy), dz = subrn(pv.z, cz);
  const float temp = sqrtf(addrn(addrn(mulrn(dx, dx), mulrn(dy, dy)), mulrn(dz, dz)));
  const float E[10]  = {pv.x, pv.y, pv.z, cx, cy, cz, dx, dy, dz, temp};
  const float X4[4]  = {pv.x, pv.y, pv.z, pw};
  const float2* stb = stats + b * 64;

  float feat[64];
  for (int o = 0; o < 32; ++o){       // xc
    float v = 0.f;
#pragma unroll
    for (int c = 0; c < 4; ++c) v = fmaf(conv_w[o * 4 + c], X4[c], v);
    const float2 sc = stb[o];
    feat[o] = leaky(fmaf(v, sc.x, sc.y), 0.2f);
  }
  for (int o = 0; o < 32; ++o){       // pe
    float v = 0.f;
#pragma unroll
    for (int c = 0; c < 10; ++c) v = fmaf(pos_w[o * 10 + c], E[c], v);
    const float2 sc = stb[32 + o];
    feat[32 + o] = leaky(fmaf(v, sc.x, sc.y), 0.2f);
  }

  float logit = 0.f;
  for (int h = 0; h < 32; ++h){
    float v = 0.f;
#pragma unroll
    for (int c = 0; c < 64; ++c) v = fmaf(att_w1[h * 64 + c], feat[c], v);
    logit = fmaf(att_w2[h], leaky(v, 0.2f), logit);
  }
  float mx = logit;
  mx = fmaxf(mx, __shfl_xor(mx, 1, 16)); mx = fmaxf(mx, __shfl_xor(mx, 2, 16));
  mx = fmaxf(mx, __shfl_xor(mx, 4, 16)); mx = fmaxf(mx, __shfl_xor(mx, 8, 16));
  const float e = expf(logit - mx);
  float den = e;
  den += __shfl_xor(den, 1, 16); den += __shfl_xor(den, 2, 16);
  den += __shfl_xor(den, 4, 16); den += __shfl_xor(den, 8, 16);
  const float att = e / den;

#pragma unroll
  for (int c = 0; c < 64; ++c){       // pooled (replicated on all 16 lanes)
    float p = feat[c] * att;
    p += __shfl_xor(p, 1, 16); p += __shfl_xor(p, 2, 16);
    p += __shfl_xor(p, 4, 16); p += __shfl_xor(p, 8, 16);
    feat[c] = p;
  }

  const float X0[4] = {cx, cy, cz, cw};
  float* outb = out + (size_t)b * 68 * Sn;
#pragma unroll
  for (int jj = 0; jj < 4; ++jj){
    const int j = k * 4 + jj;
    float f1 = 0.f;
#pragma unroll
    for (int c = 0; c < 64; ++c) f1 = fmaf(b1_w[j * 64 + c], feat[c], f1);
    float f2 = 0.f;
#pragma unroll
    for (int c = 0; c < 4; ++c) f2 = fmaf(b2_w[j * 4 + c], X0[c], f2);
    outb[(size_t)(4 + j) * Sn + sp] = leaky(f1 + f2, 0.1f);
  }
  if (k == 0){
    outb[0 * Sn + sp] = cx; outb[1 * Sn + sp] = cy;
    outb[2 * Sn + sp] = cz; outb[3 * Sn + sp] = cw;
  }
}

extern "C" void kernel_launch(void* const* d_in, const int* in_sizes, int n_in,
                              void* d_out, int out_size, void* d_ws, size_t ws_size,
                              hipStream_t stream){
  const float* x      = (const float*)d_in[0];
  const int*   perm   = (const int*)d_in[1];
  const float* pos_w  = (const float*)d_in[3];
  const float* bn2_g  = (const float*)d_in[4];
  const float* bn2_b  = (const float*)d_in[5];
  const float* conv_w = (const float*)d_in[6];
  const float* bn_g   = (const float*)d_in[7];
  const float* bn_b   = (const float*)d_in[8];
  const float* att_w1 = (const float*)d_in[9];
  const float* att_w2 = (const float*)d_in[10];
  const float* b1_w   = (const float*)d_in[11];
  const float* b2_w   = (const float*)d_in[12];
  float* out = (float*)d_out;

  char* ws = (char*)d_ws;
  int*    idx   = (int*)ws;                       // 2 MiB
  float4* pk    = (float4*)(ws + 2097152);        // 1 MiB
  float*  part  = (float*)(ws + 3145728);         // 192 KiB (4*128*96*4B)
  float2* stats = (float2*)(ws + 3342336);        // 2 KiB

  hipLaunchKernelGGL(k_pack,   dim3(256),            dim3(256),  0, stream, x, pk);
  hipLaunchKernelGGL(k_topk,   dim3(128, 4),         dim3(1024), 0, stream, pk, perm, idx);
  hipLaunchKernelGGL(k_stats,  dim3(ST_CHUNKS, 4),   dim3(256),  0, stream, pk, x, idx, part);
  hipLaunchKernelGGL(k_stats2, dim3(1),              dim3(640),  0, stream, part, pos_w, conv_w,
                     bn2_g, bn2_b, bn_g, bn_b, stats);
  hipLaunchKernelGGL(k_final,  dim3(512, 4),         dim3(256),  0, stream, pk, x, idx, stats,
                     conv_w, pos_w, att_w1, att_w2, b1_w, b2_w, out);
}